// Round 2
// baseline (162.984 us; speedup 1.0000x reference)
//
#include <hip/hip_runtime.h>
#include <hip/hip_bf16.h>
#include <math.h>

// Problem constants (NonLocalBlock): B=4, C=64, H=W=64 -> N=4096, CI=32
// Inputs/outputs are float32 (per reference); bf16 used internally for MFMA.
#define B_  4
#define C_  64
#define N_  4096
#define CI_ 32

typedef __attribute__((ext_vector_type(8))) unsigned short u16x8;
typedef __attribute__((ext_vector_type(8))) __bf16        bf16x8;
typedef __attribute__((ext_vector_type(4))) float         f32x4;

__device__ __forceinline__ unsigned short f2bf(float f) {
    union { float f; unsigned int i; } v; v.f = f;
    unsigned int r = v.i + 0x7FFFu + ((v.i >> 16) & 1u);
    return (unsigned short)(r >> 16);
}

// ---------------------------------------------------------------------------
// Kernel 1: x[b][c][n] (f32) -> xT[b][n][c] (bf16), LDS-tiled 64x64
// ---------------------------------------------------------------------------
__global__ void k_transpose(const float* __restrict__ x,
                            unsigned short* __restrict__ xT) {
    __shared__ __align__(16) unsigned short tile[64][72];   // pad 72: bank-decorrelate
    const int t  = threadIdx.x;
    const int bi = blockIdx.x;
    const int b  = bi >> 6;
    const int n0 = (bi & 63) * 64;

    #pragma unroll
    for (int it = 0; it < 2; ++it) {
        int c  = (t >> 3) + it * 32;
        int ch = (t & 7) * 8;
        const float* src = x + (size_t)(b * C_ + c) * N_ + n0 + ch;
        float4 f0 = *(const float4*)src;
        float4 f1 = *(const float4*)(src + 4);
        unsigned short* dst = &tile[c][ch];
        dst[0] = f2bf(f0.x); dst[1] = f2bf(f0.y); dst[2] = f2bf(f0.z); dst[3] = f2bf(f0.w);
        dst[4] = f2bf(f1.x); dst[5] = f2bf(f1.y); dst[6] = f2bf(f1.z); dst[7] = f2bf(f1.w);
    }
    __syncthreads();

    const int n  = t >> 2;
    const int cc = (t & 3) * 16;
    u16x8 a, bb;
    #pragma unroll
    for (int j = 0; j < 8; ++j) a[j]  = tile[cc + j][n];
    #pragma unroll
    for (int j = 0; j < 8; ++j) bb[j] = tile[cc + 8 + j][n];
    unsigned short* dst = xT + (size_t)(b * N_ + n0 + n) * C_ + cc;
    *(u16x8*)dst       = a;
    *(u16x8*)(dst + 8) = bb;
}

// ---------------------------------------------------------------------------
// Kernel 2: gx[b][o][n] = sum_c Wg[o][c]*x[b][c][n] + bg[o]   (f32 in, bf16 out)
// One block = 256 n-positions, all 32 o. x read exactly once.
// ---------------------------------------------------------------------------
__global__ __launch_bounds__(256) void k_gx(const float* __restrict__ x,
                                            const float* __restrict__ Wg,
                                            const float* __restrict__ bg,
                                            unsigned short* __restrict__ gx) {
    __shared__ float wg[CI_][C_ + 1];
    __shared__ float bgl[CI_];
    const int t  = threadIdx.x;
    const int bi = blockIdx.x;
    const int b  = bi >> 4;
    const int n  = (bi & 15) * 256 + t;

    for (int i = t; i < CI_ * C_; i += 256) wg[i >> 6][i & 63] = Wg[i];
    if (t < CI_) bgl[t] = bg[t];
    __syncthreads();

    float acc[CI_];
    #pragma unroll
    for (int o = 0; o < CI_; ++o) acc[o] = bgl[o];
    const float* xb = x + (size_t)b * C_ * N_ + n;
    #pragma unroll 8
    for (int c = 0; c < C_; ++c) {
        float xv = xb[(size_t)c * N_];
        #pragma unroll
        for (int o = 0; o < CI_; ++o) acc[o] += wg[o][c] * xv;
    }
    #pragma unroll
    for (int o = 0; o < CI_; ++o)
        gx[(size_t)(b * CI_ + o) * N_ + n] = f2bf(acc[o]);
}

// ---------------------------------------------------------------------------
// Kernel 3: fused flash attention + Wz epilogue + residual.
// Grid: 256 blocks (b * 64 q-tiles of 64 queries). Block: 512 threads = 8 waves.
//   wave -> group g = wave>>1 (key range g*1024..+1024), qhalf = wave&1 (32 queries).
// MFMA 16x16x32 bf16; verified layouts:
//   A: [m=lane&15][k=quad*8+j]   B: [k=quad*8+j][n=lane&15]   D: row=quad*4+r, col=lane&15
// ---------------------------------------------------------------------------
__device__ __forceinline__ f32x4 mfma16(bf16x8 a, bf16x8 b, f32x4 c) {
    return __builtin_amdgcn_mfma_f32_16x16x32_bf16(a, b, c, 0, 0, 0);
}

__global__ __launch_bounds__(512, 2) void k_flash(
    const unsigned short* __restrict__ xT, const unsigned short* __restrict__ gx,
    const float* __restrict__ x,  const float* __restrict__ Wz,
    const float* __restrict__ bz, float* __restrict__ out)
{
    __shared__ __align__(16) char smem[49152];
    unsigned short* xk = (unsigned short*)smem;             // [4][32 key][72 c]
    unsigned short* vt = (unsigned short*)(smem + 18432);   // [4][32 o][40 key]
    unsigned short* Pl = (unsigned short*)(smem + 28672);   // [8][32 q][40 key]

    const int tid  = threadIdx.x;
    const int wave = tid >> 6, lane = tid & 63;
    const int quad = lane >> 4, li = lane & 15;
    const int g = wave >> 1, qh = wave & 1;
    const int bi = blockIdx.x;
    const int b  = bi >> 6;
    const int q0 = (bi & 63) * 64;
    const int qw = q0 + qh * 32;        // wave's first query
    const int u  = tid & 127;           // thread id within key-group

    // Q fragments (B-operand), resident in registers the whole kernel
    bf16x8 Qf[2][2];
    #pragma unroll
    for (int qt = 0; qt < 2; ++qt)
        #pragma unroll
        for (int kc = 0; kc < 2; ++kc)
            Qf[qt][kc] = *(const bf16x8*)(xT + (size_t)(b * N_ + qw + qt * 16 + li) * C_
                                          + kc * 32 + quad * 8);

    f32x4 Yf[2][2];
    #pragma unroll
    for (int qt = 0; qt < 2; ++qt)
        #pragma unroll
        for (int ot = 0; ot < 2; ++ot)
            Yf[qt][ot] = (f32x4){0.f, 0.f, 0.f, 0.f};
    float m_run[2] = {-INFINITY, -INFINITY};
    float l_run[2] = {0.f, 0.f};

    const int keybase = g * 1024;

    for (int tl = 0; tl < 32; ++tl) {
        const int k0 = keybase + tl * 32;
        __syncthreads();   // previous iteration's consumers done
        // ---- stage K tile [32 key][64 c] and V tile [32 o][32 key] (per group) ----
        #pragma unroll
        for (int j = 0; j < 2; ++j) {
            int cc2 = u * 2 + j;
            int key = cc2 >> 3, coff = (cc2 & 7) * 8;
            *(u16x8*)(xk + (g * 32 + key) * 72 + coff) =
                *(const u16x8*)(xT + (size_t)(b * N_ + k0 + key) * C_ + coff);
        }
        {
            int o = u >> 2, koff = (u & 3) * 8;
            *(u16x8*)(vt + (g * 32 + o) * 40 + koff) =
                *(const u16x8*)(gx + (size_t)(b * CI_ + o) * N_ + k0 + koff);
        }
        __syncthreads();

        // ---- S^T = Xk (32key x 64c) * Q (64c x 32q) ----
        bf16x8 A[2][2];
        #pragma unroll
        for (int kt = 0; kt < 2; ++kt)
            #pragma unroll
            for (int kc = 0; kc < 2; ++kc)
                A[kt][kc] = *(const bf16x8*)(xk + (g * 32 + kt * 16 + li) * 72
                                             + kc * 32 + quad * 8);
        f32x4 S[2][2];
        #pragma unroll
        for (int kt = 0; kt < 2; ++kt)
            #pragma unroll
            for (int qt = 0; qt < 2; ++qt) {
                f32x4 z = (f32x4){0.f, 0.f, 0.f, 0.f};
                z = mfma16(A[kt][0], Qf[qt][0], z);
                S[kt][qt] = mfma16(A[kt][1], Qf[qt][1], z);
            }

        // ---- online softmax (per query = li, replicated over quads) ----
        #pragma unroll
        for (int qt = 0; qt < 2; ++qt) {
            float mx = -INFINITY;
            #pragma unroll
            for (int kt = 0; kt < 2; ++kt)
                #pragma unroll
                for (int r = 0; r < 4; ++r) mx = fmaxf(mx, S[kt][qt][r]);
            mx = fmaxf(mx, __shfl_xor(mx, 16, 64));
            mx = fmaxf(mx, __shfl_xor(mx, 32, 64));
            float mnew = fmaxf(m_run[qt], mx);
            float corr = __expf(m_run[qt] - mnew);   // 0 on first tile (-inf)
            m_run[qt] = mnew;

            float p[2][4]; float ps = 0.f;
            #pragma unroll
            for (int kt = 0; kt < 2; ++kt)
                #pragma unroll
                for (int r = 0; r < 4; ++r) {
                    p[kt][r] = __expf(S[kt][qt][r] - mnew);
                    ps += p[kt][r];
                }
            ps += __shfl_xor(ps, 16, 64);
            ps += __shfl_xor(ps, 32, 64);
            l_run[qt] = l_run[qt] * corr + ps;

            // pack P (bf16) into LDS in A-operand layout [q][key]
            #pragma unroll
            for (int kt = 0; kt < 2; ++kt) {
                uint2 wv;
                wv.x = (unsigned)f2bf(p[kt][0]) | ((unsigned)f2bf(p[kt][1]) << 16);
                wv.y = (unsigned)f2bf(p[kt][2]) | ((unsigned)f2bf(p[kt][3]) << 16);
                *(uint2*)(Pl + (wave * 32 + qt * 16 + li) * 40 + kt * 16 + quad * 4) = wv;
            }
            // rescale Y accumulator (its rows are q = quad*4+r -> fetch corr via shfl)
            #pragma unroll
            for (int r = 0; r < 4; ++r) {
                float cr = __shfl(corr, quad * 4 + r, 64);
                Yf[qt][0][r] *= cr;
                Yf[qt][1][r] *= cr;
            }
        }

        // ---- Y += P (32q x 32key) * V (32key x 32o) ----
        bf16x8 Ap[2], Bv[2];
        #pragma unroll
        for (int qt = 0; qt < 2; ++qt)
            Ap[qt] = *(const bf16x8*)(Pl + (wave * 32 + qt * 16 + li) * 40 + quad * 8);
        #pragma unroll
        for (int ot = 0; ot < 2; ++ot)
            Bv[ot] = *(const bf16x8*)(vt + (g * 32 + ot * 16 + li) * 40 + quad * 8);
        #pragma unroll
        for (int qt = 0; qt < 2; ++qt)
            #pragma unroll
            for (int ot = 0; ot < 2; ++ot)
                Yf[qt][ot] = mfma16(Ap[qt], Bv[ot], Yf[qt][ot]);
    }

    __syncthreads();
    // ---- merge 4 key-groups + epilogue (alias smem; all tile data dead) ----
    float* ym   = (float*)smem;            // [8 wave][32 q][33] y partials
    float* ml   = (float*)(smem + 33792);  // [8 wave][32 q][2]  (m, l)
    float* yfin = (float*)(smem + 35840);  // [64 q][33]

    #pragma unroll
    for (int qt = 0; qt < 2; ++qt) {
        #pragma unroll
        for (int ot = 0; ot < 2; ++ot)
            #pragma unroll
            for (int r = 0; r < 4; ++r)
                ym[(wave * 32 + qt * 16 + quad * 4 + r) * 33 + ot * 16 + li] = Yf[qt][ot][r];
        if (quad == 0) {
            ml[(wave * 32 + qt * 16 + li) * 2 + 0] = m_run[qt];
            ml[(wave * 32 + qt * 16 + li) * 2 + 1] = l_run[qt];
        }
    }
    __syncthreads();
    {
        const int qbar = tid >> 3, og = tid & 7;
        const int qh2 = qbar >> 5, ql = qbar & 31;
        float mg[4], lg[4], M = -INFINITY;
        #pragma unroll
        for (int gg = 0; gg < 4; ++gg) {
            int w = gg * 2 + qh2;
            mg[gg] = ml[(w * 32 + ql) * 2 + 0];
            lg[gg] = ml[(w * 32 + ql) * 2 + 1];
            M = fmaxf(M, mg[gg]);
        }
        float denom = 0.f, fc[4];
        #pragma unroll
        for (int gg = 0; gg < 4; ++gg) {
            fc[gg] = __expf(mg[gg] - M);
            denom += lg[gg] * fc[gg];
        }
        float inv = 1.f / denom;
        #pragma unroll
        for (int j = 0; j < 4; ++j) {
            int o = og * 4 + j;
            float acc = 0.f;
            #pragma unroll
            for (int gg = 0; gg < 4; ++gg)
                acc += ym[((gg * 2 + qh2) * 32 + ql) * 33 + o] * fc[gg];
            yfin[qbar * 33 + o] = acc * inv;
        }
    }
    __syncthreads();
    {
        const int q = tid & 63, c0 = tid >> 6;
        #pragma unroll
        for (int i = 0; i < 8; ++i) {
            int cout = c0 + i * 8;
            float acc = bz[cout];
            #pragma unroll
            for (int o = 0; o < CI_; ++o)
                acc += Wz[cout * CI_ + o] * yfin[q * 33 + o];
            size_t oidx = (size_t)(b * C_ + cout) * N_ + q0 + q;
            out[oidx] = acc + x[oidx];
        }
    }
}

// ---------------------------------------------------------------------------
extern "C" void kernel_launch(void* const* d_in, const int* in_sizes, int n_in,
                              void* d_out, int out_size, void* d_ws, size_t ws_size,
                              hipStream_t stream) {
    (void)in_sizes; (void)n_in; (void)out_size; (void)ws_size;
    const float* x  = (const float*)d_in[0];
    const float* Wg = (const float*)d_in[1];
    const float* bg = (const float*)d_in[2];
    const float* Wz = (const float*)d_in[3];
    const float* bz = (const float*)d_in[4];
    float* out = (float*)d_out;

    unsigned short* xT = (unsigned short*)d_ws;                     // 2 MB  [B][N][C] bf16
    unsigned short* gx = (unsigned short*)((char*)d_ws + 2097152);  // 1 MB  [B][CI][N] bf16

    hipLaunchKernelGGL(k_transpose, dim3(B_ * (N_ / 64)), dim3(256), 0, stream, x, xT);
    hipLaunchKernelGGL(k_gx, dim3(B_ * (N_ / 256)), dim3(256), 0, stream, x, Wg, bg, gx);
    hipLaunchKernelGGL(k_flash, dim3(B_ * (N_ / 64)), dim3(512), 0, stream, xT, gx, x, Wz, bz, out);
}

// Round 3
// 130.133 us; speedup vs baseline: 1.2524x; 1.2524x over previous
//
#include <hip/hip_runtime.h>
#include <hip/hip_bf16.h>
#include <math.h>

// Problem constants (NonLocalBlock): B=4, C=64, H=W=64 -> N=4096, CI=32
// Inputs/outputs are float32 (per reference); bf16 used internally for MFMA.
#define B_  4
#define C_  64
#define N_  4096
#define CI_ 32

typedef __attribute__((ext_vector_type(8))) unsigned short u16x8;
typedef __attribute__((ext_vector_type(8))) __bf16        bf16x8;
typedef __attribute__((ext_vector_type(4))) float         f32x4;

__device__ __forceinline__ unsigned short f2bf(float f) {
    union { float f; unsigned int i; } v; v.f = f;
    unsigned int r = v.i + 0x7FFFu + ((v.i >> 16) & 1u);
    return (unsigned short)(r >> 16);
}

// ---------------------------------------------------------------------------
// Kernel 1: x[b][c][n] (f32) -> xT[b][n][c] (bf16), LDS-tiled 64x64
// ---------------------------------------------------------------------------
__global__ void k_transpose(const float* __restrict__ x,
                            unsigned short* __restrict__ xT) {
    __shared__ __align__(16) unsigned short tile[64][72];
    const int t  = threadIdx.x;
    const int bi = blockIdx.x;
    const int b  = bi >> 6;
    const int n0 = (bi & 63) * 64;

    #pragma unroll
    for (int it = 0; it < 2; ++it) {
        int c  = (t >> 3) + it * 32;
        int ch = (t & 7) * 8;
        const float* src = x + (size_t)(b * C_ + c) * N_ + n0 + ch;
        float4 f0 = *(const float4*)src;
        float4 f1 = *(const float4*)(src + 4);
        unsigned short* dst = &tile[c][ch];
        dst[0] = f2bf(f0.x); dst[1] = f2bf(f0.y); dst[2] = f2bf(f0.z); dst[3] = f2bf(f0.w);
        dst[4] = f2bf(f1.x); dst[5] = f2bf(f1.y); dst[6] = f2bf(f1.z); dst[7] = f2bf(f1.w);
    }
    __syncthreads();

    const int n  = t >> 2;
    const int cc = (t & 3) * 16;
    u16x8 a, bb;
    #pragma unroll
    for (int j = 0; j < 8; ++j) a[j]  = tile[cc + j][n];
    #pragma unroll
    for (int j = 0; j < 8; ++j) bb[j] = tile[cc + 8 + j][n];
    unsigned short* dst = xT + (size_t)(b * N_ + n0 + n) * C_ + cc;
    *(u16x8*)dst       = a;
    *(u16x8*)(dst + 8) = bb;
}

// ---------------------------------------------------------------------------
// Kernel 2: gx[b][o][n] = sum_c Wg[o][c]*x[b][c][n] + bg[o]   (f32 in, bf16 out)
// 256 blocks; block = 64 n, c split 4-way across thread groups, LDS reduce.
// Wg reads are wave-uniform -> s_load broadcast.
// ---------------------------------------------------------------------------
__global__ __launch_bounds__(256) void k_gx(const float* __restrict__ x,
                                            const float* __restrict__ Wg,
                                            const float* __restrict__ bg,
                                            unsigned short* __restrict__ gx) {
    __shared__ float part[4][64][33];
    const int t  = threadIdx.x;
    const int b  = blockIdx.x >> 6;
    const int n0 = (blockIdx.x & 63) * 64;
    const int nl = t & 63, cq = t >> 6;

    float acc[CI_];
    #pragma unroll
    for (int o = 0; o < CI_; ++o) acc[o] = 0.f;
    #pragma unroll 4
    for (int cl = 0; cl < 16; ++cl) {
        int c = cq * 16 + cl;
        float xv = x[(size_t)(b * C_ + c) * N_ + n0 + nl];
        #pragma unroll
        for (int o = 0; o < CI_; ++o) acc[o] += Wg[o * C_ + c] * xv;
    }
    #pragma unroll
    for (int o = 0; o < CI_; ++o) part[cq][nl][o] = acc[o];
    __syncthreads();

    const int o = t >> 3, nr = (t & 7) * 8;
    #pragma unroll
    for (int j = 0; j < 8; ++j) {
        int n = nr + j;
        float s = part[0][n][o] + part[1][n][o] + part[2][n][o] + part[3][n][o]
                + bg[o];
        gx[(size_t)(b * CI_ + o) * N_ + n0 + n] = f2bf(s);
    }
}

// ---------------------------------------------------------------------------
// Kernel 3: flash attention partial. Grid: 1024 blocks = b(4) x qtile(64) x kq(4).
// Block: 256 threads = 4 waves; wave -> g = wave>>1 (512-key half of the
// 1024-key quarter), qh = wave&1 (32 of the 64 queries). 16 tiles of 32 keys.
// Emits unnormalized partial (m, l, Y[64q][32o]) per block.
// MFMA 16x16x32 bf16 layouts (verified):
//   A: [m=lane&15][k=quad*8+j]  B: [k=quad*8+j][n=lane&15]  D: row=quad*4+r, col=lane&15
// ---------------------------------------------------------------------------
__device__ __forceinline__ f32x4 mfma16(bf16x8 a, bf16x8 b, f32x4 c) {
    return __builtin_amdgcn_mfma_f32_16x16x32_bf16(a, b, c, 0, 0, 0);
}

__global__ __launch_bounds__(256, 4) void k_flash(
    const unsigned short* __restrict__ xT, const unsigned short* __restrict__ gx,
    float* __restrict__ ypart, float* __restrict__ mlpart)
{
    __shared__ __align__(16) char smem[24576];
    unsigned short* xk = (unsigned short*)smem;             // [2][32 key][72 c]
    unsigned short* vt = (unsigned short*)(smem + 9216);    // [2][32 o][40 key]
    unsigned short* Pl = (unsigned short*)(smem + 14336);   // [4][32 q][40 key]

    const int tid  = threadIdx.x;
    const int wave = tid >> 6, lane = tid & 63;
    const int quad = lane >> 4, li = lane & 15;
    const int g = wave >> 1, qh = wave & 1;
    const int bi  = blockIdx.x;
    const int kq  = bi & 3;
    const int qtb = (bi >> 2) & 63;
    const int b   = bi >> 8;
    const int q0  = qtb * 64;
    const int qw  = q0 + qh * 32;       // wave's first query
    const int u   = tid & 127;          // thread id within key-group

    // Q fragments (B-operand), resident in registers the whole kernel
    bf16x8 Qf[2][2];
    #pragma unroll
    for (int qt = 0; qt < 2; ++qt)
        #pragma unroll
        for (int kc = 0; kc < 2; ++kc)
            Qf[qt][kc] = *(const bf16x8*)(xT + (size_t)(b * N_ + qw + qt * 16 + li) * C_
                                          + kc * 32 + quad * 8);

    f32x4 Yf[2][2];
    #pragma unroll
    for (int qt = 0; qt < 2; ++qt)
        #pragma unroll
        for (int ot = 0; ot < 2; ++ot)
            Yf[qt][ot] = (f32x4){0.f, 0.f, 0.f, 0.f};
    float m_run[2] = {-INFINITY, -INFINITY};
    float l_run[2] = {0.f, 0.f};

    const int keybase = kq * 1024 + g * 512;

    for (int tl = 0; tl < 16; ++tl) {
        const int k0 = keybase + tl * 32;
        __syncthreads();   // previous iteration's consumers done
        // ---- stage K tile [32 key][64 c] and V tile [32 o][32 key] (per group) ----
        #pragma unroll
        for (int j = 0; j < 2; ++j) {
            int cc2 = u * 2 + j;
            int key = cc2 >> 3, coff = (cc2 & 7) * 8;
            *(u16x8*)(xk + (g * 32 + key) * 72 + coff) =
                *(const u16x8*)(xT + (size_t)(b * N_ + k0 + key) * C_ + coff);
        }
        {
            int o = u >> 2, koff = (u & 3) * 8;
            *(u16x8*)(vt + (g * 32 + o) * 40 + koff) =
                *(const u16x8*)(gx + (size_t)(b * CI_ + o) * N_ + k0 + koff);
        }
        __syncthreads();

        // ---- S^T = Xk (32key x 64c) * Q (64c x 32q) ----
        bf16x8 A[2][2];
        #pragma unroll
        for (int kt = 0; kt < 2; ++kt)
            #pragma unroll
            for (int kc = 0; kc < 2; ++kc)
                A[kt][kc] = *(const bf16x8*)(xk + (g * 32 + kt * 16 + li) * 72
                                             + kc * 32 + quad * 8);
        f32x4 S[2][2];
        #pragma unroll
        for (int kt = 0; kt < 2; ++kt)
            #pragma unroll
            for (int qt = 0; qt < 2; ++qt) {
                f32x4 z = (f32x4){0.f, 0.f, 0.f, 0.f};
                z = mfma16(A[kt][0], Qf[qt][0], z);
                S[kt][qt] = mfma16(A[kt][1], Qf[qt][1], z);
            }

        // ---- online softmax (per query = li, replicated over quads) ----
        #pragma unroll
        for (int qt = 0; qt < 2; ++qt) {
            float mx = -INFINITY;
            #pragma unroll
            for (int kt = 0; kt < 2; ++kt)
                #pragma unroll
                for (int r = 0; r < 4; ++r) mx = fmaxf(mx, S[kt][qt][r]);
            mx = fmaxf(mx, __shfl_xor(mx, 16, 64));
            mx = fmaxf(mx, __shfl_xor(mx, 32, 64));
            float mnew = fmaxf(m_run[qt], mx);
            float corr = __expf(m_run[qt] - mnew);   // 0 on first tile (-inf)
            m_run[qt] = mnew;

            float p[2][4]; float ps = 0.f;
            #pragma unroll
            for (int kt = 0; kt < 2; ++kt)
                #pragma unroll
                for (int r = 0; r < 4; ++r) {
                    p[kt][r] = __expf(S[kt][qt][r] - mnew);
                    ps += p[kt][r];
                }
            ps += __shfl_xor(ps, 16, 64);
            ps += __shfl_xor(ps, 32, 64);
            l_run[qt] = l_run[qt] * corr + ps;

            // pack P (bf16) into LDS in A-operand layout [q][key]
            #pragma unroll
            for (int kt = 0; kt < 2; ++kt) {
                uint2 wv;
                wv.x = (unsigned)f2bf(p[kt][0]) | ((unsigned)f2bf(p[kt][1]) << 16);
                wv.y = (unsigned)f2bf(p[kt][2]) | ((unsigned)f2bf(p[kt][3]) << 16);
                *(uint2*)(Pl + (wave * 32 + qt * 16 + li) * 40 + kt * 16 + quad * 4) = wv;
            }
            // rescale Y accumulator (rows are q = quad*4+r -> fetch corr via shfl)
            #pragma unroll
            for (int r = 0; r < 4; ++r) {
                float cr = __shfl(corr, quad * 4 + r, 64);
                Yf[qt][0][r] *= cr;
                Yf[qt][1][r] *= cr;
            }
        }

        // ---- Y += P (32q x 32key) * V (32key x 32o) ----
        bf16x8 Ap[2], Bv[2];
        #pragma unroll
        for (int qt = 0; qt < 2; ++qt)
            Ap[qt] = *(const bf16x8*)(Pl + (wave * 32 + qt * 16 + li) * 40 + quad * 8);
        #pragma unroll
        for (int ot = 0; ot < 2; ++ot)
            Bv[ot] = *(const bf16x8*)(vt + (g * 32 + ot * 16 + li) * 40 + quad * 8);
        #pragma unroll
        for (int qt = 0; qt < 2; ++qt)
            #pragma unroll
            for (int ot = 0; ot < 2; ++ot)
                Yf[qt][ot] = mfma16(Ap[qt], Bv[ot], Yf[qt][ot]);
    }

    __syncthreads();
    // ---- combine this block's 2 key-groups -> unnormalized partial ----
    float* ym = (float*)smem;             // [4 wave][32 q][33] y partials
    float* ml = (float*)(smem + 16896);   // [4 wave][32 q][2]  (m, l)

    #pragma unroll
    for (int qt = 0; qt < 2; ++qt) {
        #pragma unroll
        for (int ot = 0; ot < 2; ++ot)
            #pragma unroll
            for (int r = 0; r < 4; ++r)
                ym[(wave * 32 + qt * 16 + quad * 4 + r) * 33 + ot * 16 + li] = Yf[qt][ot][r];
        if (quad == 0) {
            ml[(wave * 32 + qt * 16 + li) * 2 + 0] = m_run[qt];
            ml[(wave * 32 + qt * 16 + li) * 2 + 1] = l_run[qt];
        }
    }
    __syncthreads();
    {
        const int q = tid >> 2, og = tid & 3;
        const int qh2 = q >> 5, ql = q & 31;
        float m0 = ml[((0 * 2 + qh2) * 32 + ql) * 2 + 0];
        float l0 = ml[((0 * 2 + qh2) * 32 + ql) * 2 + 1];
        float m1 = ml[((1 * 2 + qh2) * 32 + ql) * 2 + 0];
        float l1 = ml[((1 * 2 + qh2) * 32 + ql) * 2 + 1];
        float M  = fmaxf(m0, m1);
        float f0 = __expf(m0 - M), f1 = __expf(m1 - M);
        const size_t pbase = (size_t)(b * 64 + qtb) * 4 + kq;
        float* yp = ypart + pbase * 2048 + q * 32;
        #pragma unroll
        for (int j = 0; j < 8; ++j) {
            int o = og * 8 + j;
            yp[o] = ym[((0 * 2 + qh2) * 32 + ql) * 33 + o] * f0
                  + ym[((1 * 2 + qh2) * 32 + ql) * 33 + o] * f1;
        }
        if (og == 0) {
            mlpart[pbase * 128 + q * 2 + 0] = M;
            mlpart[pbase * 128 + q * 2 + 1] = l0 * f0 + l1 * f1;
        }
    }
}

// ---------------------------------------------------------------------------
// Kernel 4: merge 4 key-quarter partials + Wz epilogue + residual.
// Grid: 256 blocks = b x qtile. Block 256 threads.
// ---------------------------------------------------------------------------
__global__ __launch_bounds__(256) void k_merge(
    const float* __restrict__ ypart, const float* __restrict__ mlpart,
    const float* __restrict__ x, const float* __restrict__ Wz,
    const float* __restrict__ bz, float* __restrict__ out)
{
    __shared__ float yfin[64][33];
    const int t   = threadIdx.x;
    const int b   = blockIdx.x >> 6;
    const int qtb = blockIdx.x & 63;
    const int q0  = qtb * 64;

    {
        const int q = t >> 2, og = t & 3;
        const size_t pb = (size_t)(b * 64 + qtb) * 4;
        float m[4], l[4], M = -INFINITY;
        #pragma unroll
        for (int kq = 0; kq < 4; ++kq) {
            m[kq] = mlpart[(pb + kq) * 128 + q * 2 + 0];
            l[kq] = mlpart[(pb + kq) * 128 + q * 2 + 1];
            M = fmaxf(M, m[kq]);
        }
        float fc[4], denom = 0.f;
        #pragma unroll
        for (int kq = 0; kq < 4; ++kq) {
            fc[kq] = __expf(m[kq] - M);
            denom += l[kq] * fc[kq];
        }
        float inv = 1.f / denom;
        #pragma unroll
        for (int j = 0; j < 8; ++j) {
            int o = og * 8 + j;
            float acc = 0.f;
            #pragma unroll
            for (int kq = 0; kq < 4; ++kq)
                acc += ypart[(pb + kq) * 2048 + q * 32 + o] * fc[kq];
            yfin[q][o] = acc * inv;
        }
    }
    __syncthreads();
    {
        const int q = t & 63, c0 = t >> 6;
        #pragma unroll
        for (int i = 0; i < 16; ++i) {
            int cout = c0 + i * 4;
            float acc = bz[cout];
            #pragma unroll
            for (int o = 0; o < CI_; ++o)
                acc += Wz[cout * CI_ + o] * yfin[q][o];
            size_t oidx = (size_t)(b * C_ + cout) * N_ + q0 + q;
            out[oidx] = acc + x[oidx];
        }
    }
}

// ---------------------------------------------------------------------------
extern "C" void kernel_launch(void* const* d_in, const int* in_sizes, int n_in,
                              void* d_out, int out_size, void* d_ws, size_t ws_size,
                              hipStream_t stream) {
    (void)in_sizes; (void)n_in; (void)out_size; (void)ws_size;
    const float* x  = (const float*)d_in[0];
    const float* Wg = (const float*)d_in[1];
    const float* bg = (const float*)d_in[2];
    const float* Wz = (const float*)d_in[3];
    const float* bz = (const float*)d_in[4];
    float* out = (float*)d_out;

    // ws layout: xT 2MB | gx 1MB | ypart 8MB | mlpart 0.5MB  (~11.5MB total)
    unsigned short* xT  = (unsigned short*)d_ws;
    unsigned short* gx  = (unsigned short*)((char*)d_ws + 2097152);
    float* ypart  = (float*)((char*)d_ws + 3145728);
    float* mlpart = (float*)((char*)d_ws + 11534336);

    hipLaunchKernelGGL(k_transpose, dim3(B_ * (N_ / 64)), dim3(256), 0, stream, x, xT);
    hipLaunchKernelGGL(k_gx, dim3(B_ * (N_ / 64)), dim3(256), 0, stream, x, Wg, bg, gx);
    hipLaunchKernelGGL(k_flash, dim3(B_ * 64 * 4), dim3(256), 0, stream, xT, gx, ypart, mlpart);
    hipLaunchKernelGGL(k_merge, dim3(B_ * 64), dim3(256), 0, stream, ypart, mlpart, x, Wz, bz, out);
}

// Round 4
// 117.941 us; speedup vs baseline: 1.3819x; 1.1034x over previous
//
#include <hip/hip_runtime.h>
#include <hip/hip_bf16.h>
#include <math.h>

// Problem constants (NonLocalBlock): B=4, C=64, H=W=64 -> N=4096, CI=32
// Inputs/outputs are float32 (per reference); bf16 used internally for MFMA.
// Softmax trick: logits s[q][k] = x_q·x_k; shift by K[q] = |x_q|^2 (diagonal).
// Cauchy-Schwarz bounds shifted logits in [-inf, ~35]; shifted diag = 0 so the
// denominator >= ~1. This makes softmax a PURE exp + linear accumulation:
// partials across key-splits combine by plain addition (no m/l merge).
#define B_  4
#define C_  64
#define N_  4096
#define CI_ 32

typedef __attribute__((ext_vector_type(8))) unsigned short u16x8;
typedef __attribute__((ext_vector_type(8))) __bf16        bf16x8;
typedef __attribute__((ext_vector_type(4))) float         f32x4;

__device__ __forceinline__ unsigned short f2bf(float f) {
    union { float f; unsigned int i; } v; v.f = f;
    unsigned int r = v.i + 0x7FFFu + ((v.i >> 16) & 1u);
    return (unsigned short)(r >> 16);
}

// ---------------------------------------------------------------------------
// Kernel 1 (fused prep): per 64-n tile of one batch:
//   xT[b][n][c] (bf16)   <- transpose of x
//   gx[b][o][n] (bf16)   <- Wg x + bg
//   diag[b][n]  (f32)    <- |x_n|^2   (the softmax shift)
// Grid 256 = b(4) x ntile(64). Block 256.
// ---------------------------------------------------------------------------
__global__ __launch_bounds__(256) void k_prep(
    const float* __restrict__ x, const float* __restrict__ Wg,
    const float* __restrict__ bg, unsigned short* __restrict__ xT,
    unsigned short* __restrict__ gx, float* __restrict__ diag)
{
    __shared__ __align__(16) float tile[64][68];   // stride 68: rows 16B-aligned
    __shared__ float part[4][64][33];              // o 0..31 = gx, col 32 = diag
    const int t  = threadIdx.x;
    const int b  = blockIdx.x >> 6;
    const int n0 = (blockIdx.x & 63) * 64;

    #pragma unroll
    for (int pass = 0; pass < 4; ++pass) {
        int c   = (t >> 4) + pass * 16;
        int nl4 = (t & 15) * 4;
        float4 v = *(const float4*)(x + (size_t)(b * C_ + c) * N_ + n0 + nl4);
        *(float4*)&tile[c][nl4] = v;
    }
    __syncthreads();

    // (a) write xT (bf16 transpose), coalesced 128B per 4 lanes
    {
        const int n  = t >> 2;
        const int cc = (t & 3) * 16;
        u16x8 a, b2;
        #pragma unroll
        for (int j = 0; j < 8; ++j) a[j]  = f2bf(tile[cc + j][n]);
        #pragma unroll
        for (int j = 0; j < 8; ++j) b2[j] = f2bf(tile[cc + 8 + j][n]);
        unsigned short* dst = xT + (size_t)(b * N_ + n0 + n) * C_ + cc;
        *(u16x8*)dst       = a;
        *(u16x8*)(dst + 8) = b2;
    }
    // (b) gx partial + diag partial
    {
        const int nl = t & 63, cq = t >> 6;
        float acc[CI_];
        #pragma unroll
        for (int o = 0; o < CI_; ++o) acc[o] = 0.f;
        float dd = 0.f;
        #pragma unroll 4
        for (int cl = 0; cl < 16; ++cl) {
            int c = cq * 16 + cl;
            float xv = tile[c][nl];
            dd += xv * xv;
            #pragma unroll
            for (int o = 0; o < CI_; ++o) acc[o] += Wg[o * C_ + c] * xv;
        }
        #pragma unroll
        for (int o = 0; o < CI_; ++o) part[cq][nl][o] = acc[o];
        part[cq][nl][32] = dd;
    }
    __syncthreads();
    // (c) reduce + write gx
    {
        const int o = t >> 3, nr = (t & 7) * 8;
        u16x8 w;
        #pragma unroll
        for (int j = 0; j < 8; ++j) {
            int n = nr + j;
            float s = part[0][n][o] + part[1][n][o] + part[2][n][o] + part[3][n][o]
                    + bg[o];
            w[j] = f2bf(s);
        }
        *(u16x8*)(gx + (size_t)(b * CI_ + o) * N_ + n0 + nr) = w;
    }
    // (d) write diag
    if (t < 64)
        diag[(size_t)b * N_ + n0 + t] =
            part[0][t][32] + part[1][t][32] + part[2][t][32] + part[3][t][32];
}

// ---------------------------------------------------------------------------
// Kernel 2: flash partial, shift-softmax (no online max). Grid 1024 =
// b(4) x qtile(64) x kq(4). Block 256 = 4 waves; g = wave>>1 (512-key half),
// qh = wave&1 (32 queries). 16 tiles of 32 keys. Emits additive partials
// (Y[64q][32o], l[64q]) per block.
// MFMA 16x16x32 bf16 layouts (verified):
//   A: [m=lane&15][k=quad*8+j]  B: [k=quad*8+j][n=lane&15]  D: row=quad*4+r, col=lane&15
// ---------------------------------------------------------------------------
__device__ __forceinline__ f32x4 mfma16(bf16x8 a, bf16x8 b, f32x4 c) {
    return __builtin_amdgcn_mfma_f32_16x16x32_bf16(a, b, c, 0, 0, 0);
}

__global__ __launch_bounds__(256, 4) void k_flash(
    const unsigned short* __restrict__ xT, const unsigned short* __restrict__ gx,
    const float* __restrict__ diag,
    float* __restrict__ ypart, float* __restrict__ lpart)
{
    __shared__ __align__(16) char smem[24576];
    unsigned short* xk = (unsigned short*)smem;             // [2][32 key][72 c]
    unsigned short* vt = (unsigned short*)(smem + 9216);    // [2][32 o][40 key]
    unsigned short* Pl = (unsigned short*)(smem + 14336);   // [4][32 q][40 key]

    const int tid  = threadIdx.x;
    const int wave = tid >> 6, lane = tid & 63;
    const int quad = lane >> 4, li = lane & 15;
    const int g = wave >> 1, qh = wave & 1;
    const int bi  = blockIdx.x;
    const int kq  = bi & 3;
    const int qtb = (bi >> 2) & 63;
    const int b   = bi >> 8;
    const int qw  = qtb * 64 + qh * 32;   // wave's first query
    const int u   = tid & 127;            // thread id within key-group

    // per-lane softmax shift: query = column li of S^T
    float Kq[2];
    #pragma unroll
    for (int qt = 0; qt < 2; ++qt)
        Kq[qt] = diag[(size_t)b * N_ + qw + qt * 16 + li];

    // Q fragments (B-operand), resident in registers
    bf16x8 Qf[2][2];
    #pragma unroll
    for (int qt = 0; qt < 2; ++qt)
        #pragma unroll
        for (int kc = 0; kc < 2; ++kc)
            Qf[qt][kc] = *(const bf16x8*)(xT + (size_t)(b * N_ + qw + qt * 16 + li) * C_
                                          + kc * 32 + quad * 8);

    f32x4 Yf[2][2];
    #pragma unroll
    for (int qt = 0; qt < 2; ++qt)
        #pragma unroll
        for (int ot = 0; ot < 2; ++ot)
            Yf[qt][ot] = (f32x4){0.f, 0.f, 0.f, 0.f};
    float lacc[2] = {0.f, 0.f};

    const int keybase = kq * 1024 + g * 512;

    for (int tl = 0; tl < 16; ++tl) {
        const int k0 = keybase + tl * 32;
        __syncthreads();
        // ---- stage K tile [32 key][64 c] and V tile [32 o][32 key] per group ----
        #pragma unroll
        for (int j = 0; j < 2; ++j) {
            int cc2 = u * 2 + j;
            int key = cc2 >> 3, coff = (cc2 & 7) * 8;
            *(u16x8*)(xk + (g * 32 + key) * 72 + coff) =
                *(const u16x8*)(xT + (size_t)(b * N_ + k0 + key) * C_ + coff);
        }
        {
            int o = u >> 2, koff = (u & 3) * 8;
            *(u16x8*)(vt + (g * 32 + o) * 40 + koff) =
                *(const u16x8*)(gx + (size_t)(b * CI_ + o) * N_ + k0 + koff);
        }
        __syncthreads();

        // ---- S^T = Xk (32key x 64c) * Q (64c x 32q) ----
        bf16x8 A[2][2];
        #pragma unroll
        for (int kt = 0; kt < 2; ++kt)
            #pragma unroll
            for (int kc = 0; kc < 2; ++kc)
                A[kt][kc] = *(const bf16x8*)(xk + (g * 32 + kt * 16 + li) * 72
                                             + kc * 32 + quad * 8);
        f32x4 S[2][2];
        #pragma unroll
        for (int kt = 0; kt < 2; ++kt)
            #pragma unroll
            for (int qt = 0; qt < 2; ++qt) {
                f32x4 z = (f32x4){0.f, 0.f, 0.f, 0.f};
                z = mfma16(A[kt][0], Qf[qt][0], z);
                S[kt][qt] = mfma16(A[kt][1], Qf[qt][1], z);
            }

        // ---- p = exp(s - K[q]); accumulate l; pack P to LDS (A-layout) ----
        #pragma unroll
        for (int qt = 0; qt < 2; ++qt) {
            float p[2][4];
            #pragma unroll
            for (int kt = 0; kt < 2; ++kt)
                #pragma unroll
                for (int r = 0; r < 4; ++r) {
                    p[kt][r] = __expf(S[kt][qt][r] - Kq[qt]);
                    lacc[qt] += p[kt][r];
                }
            #pragma unroll
            for (int kt = 0; kt < 2; ++kt) {
                uint2 wv;
                wv.x = (unsigned)f2bf(p[kt][0]) | ((unsigned)f2bf(p[kt][1]) << 16);
                wv.y = (unsigned)f2bf(p[kt][2]) | ((unsigned)f2bf(p[kt][3]) << 16);
                *(uint2*)(Pl + (wave * 32 + qt * 16 + li) * 40 + kt * 16 + quad * 4) = wv;
            }
        }

        // ---- Y += P (32q x 32key) * V (32key x 32o) ----
        bf16x8 Ap[2], Bv[2];
        #pragma unroll
        for (int qt = 0; qt < 2; ++qt)
            Ap[qt] = *(const bf16x8*)(Pl + (wave * 32 + qt * 16 + li) * 40 + quad * 8);
        #pragma unroll
        for (int ot = 0; ot < 2; ++ot)
            Bv[ot] = *(const bf16x8*)(vt + (g * 32 + ot * 16 + li) * 40 + quad * 8);
        #pragma unroll
        for (int qt = 0; qt < 2; ++qt)
            #pragma unroll
            for (int ot = 0; ot < 2; ++ot)
                Yf[qt][ot] = mfma16(Ap[qt], Bv[ot], Yf[qt][ot]);
    }

    // finalize l: sum across quads (keys) -> every lane holds total for query li
    #pragma unroll
    for (int qt = 0; qt < 2; ++qt) {
        lacc[qt] += __shfl_xor(lacc[qt], 16, 64);
        lacc[qt] += __shfl_xor(lacc[qt], 32, 64);
    }

    __syncthreads();
    // ---- combine the block's 2 key-groups (plain add) -> additive partial ----
    float* ym = (float*)smem;   // [4 wave][32 q][34]: o 0..31 = Y, col 32 = l

    #pragma unroll
    for (int qt = 0; qt < 2; ++qt) {
        #pragma unroll
        for (int ot = 0; ot < 2; ++ot)
            #pragma unroll
            for (int r = 0; r < 4; ++r)
                ym[(wave * 32 + qt * 16 + quad * 4 + r) * 34 + ot * 16 + li] = Yf[qt][ot][r];
        if (quad == 0)
            ym[(wave * 32 + qt * 16 + li) * 34 + 32] = lacc[qt];
    }
    __syncthreads();
    {
        const int q = tid >> 2, og = tid & 3;
        const int qh2 = q >> 5, ql = q & 31;
        const int w0 = qh2, w1 = 2 + qh2;   // same q-half, the two key-groups
        const size_t pbase = (size_t)(b * 64 + qtb) * 4 + kq;
        float* yp = ypart + pbase * 2048 + q * 32;
        #pragma unroll
        for (int j = 0; j < 8; ++j) {
            int o = og * 8 + j;
            yp[o] = ym[(w0 * 32 + ql) * 34 + o] + ym[(w1 * 32 + ql) * 34 + o];
        }
        if (og == 0)
            lpart[pbase * 64 + q] = ym[(w0 * 32 + ql) * 34 + 32]
                                  + ym[(w1 * 32 + ql) * 34 + 32];
    }
}

// ---------------------------------------------------------------------------
// Kernel 3: merge 4 key-quarter partials (plain add) + Wz epilogue + residual.
// Grid: 256 blocks = b x qtile. Block 256 threads.
// ---------------------------------------------------------------------------
__global__ __launch_bounds__(256) void k_merge(
    const float* __restrict__ ypart, const float* __restrict__ lpart,
    const float* __restrict__ x, const float* __restrict__ Wz,
    const float* __restrict__ bz, float* __restrict__ out)
{
    __shared__ float yfin[64][33];
    const int t   = threadIdx.x;
    const int b   = blockIdx.x >> 6;
    const int qtb = blockIdx.x & 63;
    const int q0  = qtb * 64;

    {
        const int q = t >> 2, og = t & 3;
        const size_t pb = (size_t)(b * 64 + qtb) * 4;
        float l = lpart[(pb + 0) * 64 + q] + lpart[(pb + 1) * 64 + q]
                + lpart[(pb + 2) * 64 + q] + lpart[(pb + 3) * 64 + q];
        float inv = 1.f / l;
        #pragma unroll
        for (int j = 0; j < 8; ++j) {
            int o = og * 8 + j;
            float acc = 0.f;
            #pragma unroll
            for (int kq = 0; kq < 4; ++kq)
                acc += ypart[(pb + kq) * 2048 + q * 32 + o];
            yfin[q][o] = acc * inv;
        }
    }
    __syncthreads();
    {
        const int q = t & 63, c0 = t >> 6;
        #pragma unroll
        for (int i = 0; i < 16; ++i) {
            int cout = c0 + i * 4;
            float acc = bz[cout];
            #pragma unroll
            for (int o = 0; o < CI_; ++o)
                acc += Wz[cout * CI_ + o] * yfin[q][o];
            size_t oidx = (size_t)(b * C_ + cout) * N_ + q0 + q;
            out[oidx] = acc + x[oidx];
        }
    }
}

// ---------------------------------------------------------------------------
extern "C" void kernel_launch(void* const* d_in, const int* in_sizes, int n_in,
                              void* d_out, int out_size, void* d_ws, size_t ws_size,
                              hipStream_t stream) {
    (void)in_sizes; (void)n_in; (void)out_size; (void)ws_size;
    const float* x  = (const float*)d_in[0];
    const float* Wg = (const float*)d_in[1];
    const float* bg = (const float*)d_in[2];
    const float* Wz = (const float*)d_in[3];
    const float* bz = (const float*)d_in[4];
    float* out = (float*)d_out;

    // ws layout: xT 2MB | gx 1MB | diag 64KB | ypart 8MB | lpart 256KB (~11.3MB)
    unsigned short* xT = (unsigned short*)d_ws;
    unsigned short* gx = (unsigned short*)((char*)d_ws + 2097152);
    float* diag  = (float*)((char*)d_ws + 3145728);
    float* ypart = (float*)((char*)d_ws + 3211264);
    float* lpart = (float*)((char*)d_ws + 11599872);

    hipLaunchKernelGGL(k_prep,  dim3(B_ * (N_ / 64)),    dim3(256), 0, stream, x, Wg, bg, xT, gx, diag);
    hipLaunchKernelGGL(k_flash, dim3(B_ * 64 * 4),       dim3(256), 0, stream, xT, gx, diag, ypart, lpart);
    hipLaunchKernelGGL(k_merge, dim3(B_ * 64),           dim3(256), 0, stream, ypart, lpart, x, Wz, bz, out);
}